// Round 4
// baseline (476.572 us; speedup 1.0000x reference)
//
#include <hip/hip_runtime.h>

#define B_  16
#define N_  2048
#define D_  1024
#define P_  1024
#define M_  (B_*N_)   // 32768

typedef __attribute__((ext_vector_type(8))) short bf16x8;
typedef __attribute__((ext_vector_type(4))) float f32x4;

__device__ __forceinline__ float bf2f(unsigned short u) {
    union { unsigned int i; float f; } v; v.i = ((unsigned int)u) << 16; return v.f;
}
__device__ __forceinline__ unsigned short f2bf(float f) {
    union { unsigned int i; float f; } v; v.f = f;
    unsigned int i = v.i;
    return (unsigned short)((i + 0x7FFFu + ((i >> 16) & 1u)) >> 16);   // RNE
}

__device__ __forceinline__ void async_cp16(const void* g, void* s) {
    __builtin_amdgcn_global_load_lds((const __attribute__((address_space(1))) void*)g,
                                     (__attribute__((address_space(3))) void*)s,
                                     16, 0, 0);
}

// fp32 -> bf16 bulk convert (RNE), grid-stride, float4 loads / 8B stores
__global__ void cvt_k(const float* __restrict__ in, unsigned short* __restrict__ out, int n)
{
    for (int i = (blockIdx.x * 256 + threadIdx.x) * 4; i < n; i += gridDim.x * 256 * 4) {
        float4 v = *(const float4*)(in + i);
        union { unsigned short u[4]; unsigned long long ll; } p;
        p.u[0] = f2bf(v.x); p.u[1] = f2bf(v.y); p.u[2] = f2bf(v.z); p.u[3] = f2bf(v.w);
        *(unsigned long long*)(out + i) = p.ll;
    }
}

// ---------- Path A GEMM: bf16-staged (inputs pre-converted) ----------
// acc[m,p] = sum_k A[m,k]*W[p,k]; A:[M x 1024] bf16 rm, W:[1024 x 1024] bf16 rm.
// MODE 0: X1_bf16 = f2bf(relu(acc+bias));  MODE 1: out_f32 = att[m]*relu(acc+bias)
template<int MODE>
__global__ __launch_bounds__(256) void gemm_bf(const unsigned short* __restrict__ A,
                                               const unsigned short* __restrict__ W,
                                               const float* __restrict__ bias,
                                               const float* __restrict__ att,
                                               void* __restrict__ Cv)
{
    const int K = D_, BK = 32;
    __shared__ unsigned short As[128 * 32];
    __shared__ unsigned short Bs[128 * 32];

    const int wave = threadIdx.x >> 6, lane = threadIdx.x & 63;
    const int wr = wave >> 1, wc = wave & 1;
    const int m0 = blockIdx.y * 128, p0 = blockIdx.x * 128;

    const int srow = wave * 32 + (lane >> 2);     // 16 rows per inst
    const int scol = (lane & 3) * 8;              // 8 bf16 = 16B
    const unsigned short* ag = A + (size_t)(m0 + srow) * K + scol;
    const unsigned short* bg = W + (size_t)(p0 + srow) * K + scol;
    unsigned short* as = &As[srow * BK + scol];
    unsigned short* bs = &Bs[srow * BK + scol];

    f32x4 acc[4][4];
    #pragma unroll
    for (int i = 0; i < 4; i++)
        #pragma unroll
        for (int j = 0; j < 4; j++) acc[i][j] = (f32x4){0.f,0.f,0.f,0.f};

    const int lr = lane & 15, lq = lane >> 4;
    const unsigned short* Ar = &As[(wr * 64 + lr) * BK + lq * 8];
    const unsigned short* Br = &Bs[(wc * 64 + lr) * BK + lq * 8];

    for (int kb = 0; kb < K; kb += BK) {
        async_cp16(ag + kb,          as);
        async_cp16(ag + 16 * K + kb, as + 16 * BK);
        async_cp16(bg + kb,          bs);
        async_cp16(bg + 16 * K + kb, bs + 16 * BK);
        __syncthreads();
        bf16x8 af[4], bf[4];
        #pragma unroll
        for (int i = 0; i < 4; i++) af[i] = *(const bf16x8*)(Ar + i * 16 * BK);
        #pragma unroll
        for (int j = 0; j < 4; j++) bf[j] = *(const bf16x8*)(Br + j * 16 * BK);
        #pragma unroll
        for (int i = 0; i < 4; i++)
            #pragma unroll
            for (int j = 0; j < 4; j++)
                acc[i][j] = __builtin_amdgcn_mfma_f32_16x16x32_bf16(af[i], bf[j], acc[i][j], 0, 0, 0);
        __syncthreads();
    }

    // C/D layout: col = lane&15, row = (lane>>4)*4 + reg   [m89-verified]
    const int crow0 = m0 + wr * 64 + lq * 4;
    const int ccol0 = p0 + wc * 64 + lr;
    #pragma unroll
    for (int i = 0; i < 4; i++) {
        float attv[4];
        if (MODE == 1) {
            #pragma unroll
            for (int v = 0; v < 4; v++) attv[v] = att[crow0 + i * 16 + v];
        }
        #pragma unroll
        for (int j = 0; j < 4; j++) {
            const int col = ccol0 + j * 16;
            const float bi = bias[col];
            #pragma unroll
            for (int v = 0; v < 4; v++) {
                const int row = crow0 + i * 16 + v;
                float val = fmaxf(acc[i][j][v] + bi, 0.0f);
                if (MODE == 0) ((unsigned short*)Cv)[(size_t)row * P_ + col] = f2bf(val);
                else           ((float*)Cv)[(size_t)row * P_ + col] = val * attv[v];
            }
        }
    }
}

// ---------- Path B GEMM: fp32-staged, in-register truncation to bf16 ----------
template<int MODE>
__global__ __launch_bounds__(256) void gemm_f32(const float* __restrict__ A,
                                                const float* __restrict__ W,
                                                const float* __restrict__ bias,
                                                const float* __restrict__ att,
                                                void* __restrict__ Cv)
{
    const int K = D_, BK = 32;
    __shared__ float As[128 * 32];   // 16 KiB
    __shared__ float Bs[128 * 32];   // 16 KiB

    const int wave = threadIdx.x >> 6, lane = threadIdx.x & 63;
    const int wr = wave >> 1, wc = wave & 1;
    const int m0 = blockIdx.y * 128, p0 = blockIdx.x * 128;

    // 1 inst = 64 lanes x 16B = 8 fp32 rows of 128B; 4 insts per 32-row slab
    const int srow = wave * 32 + (lane >> 3);
    const int scol = (lane & 7) * 4;              // fp32 elements
    const float* ag = A + (size_t)(m0 + srow) * K + scol;
    const float* bg = W + (size_t)(p0 + srow) * K + scol;
    float* as = &As[srow * BK + scol];
    float* bs = &Bs[srow * BK + scol];

    f32x4 acc[4][4];
    #pragma unroll
    for (int i = 0; i < 4; i++)
        #pragma unroll
        for (int j = 0; j < 4; j++) acc[i][j] = (f32x4){0.f,0.f,0.f,0.f};

    const int lr = lane & 15, lq = lane >> 4;
    const float* Ar = &As[(wr * 64 + lr) * BK + lq * 8];
    const float* Br = &Bs[(wc * 64 + lr) * BK + lq * 8];

    for (int kb = 0; kb < K; kb += BK) {
        #pragma unroll
        for (int s = 0; s < 4; s++) {
            async_cp16(ag + (size_t)s * 8 * K + kb, as + s * 8 * BK);
            async_cp16(bg + (size_t)s * 8 * K + kb, bs + s * 8 * BK);
        }
        __syncthreads();
        bf16x8 af[4], bf[4];
        #pragma unroll
        for (int i = 0; i < 4; i++) {
            f32x4 a0 = *(const f32x4*)(Ar + i * 16 * BK);
            f32x4 a1 = *(const f32x4*)(Ar + i * 16 * BK + 4);
            #pragma unroll
            for (int e = 0; e < 4; e++) {
                union { float f; unsigned int u; } c;
                c.f = a0[e]; af[i][e]     = (short)(c.u >> 16);   // truncate
                c.f = a1[e]; af[i][e + 4] = (short)(c.u >> 16);
            }
        }
        #pragma unroll
        for (int j = 0; j < 4; j++) {
            f32x4 b0 = *(const f32x4*)(Br + j * 16 * BK);
            f32x4 b1 = *(const f32x4*)(Br + j * 16 * BK + 4);
            #pragma unroll
            for (int e = 0; e < 4; e++) {
                union { float f; unsigned int u; } c;
                c.f = b0[e]; bf[j][e]     = (short)(c.u >> 16);
                c.f = b1[e]; bf[j][e + 4] = (short)(c.u >> 16);
            }
        }
        #pragma unroll
        for (int i = 0; i < 4; i++)
            #pragma unroll
            for (int j = 0; j < 4; j++)
                acc[i][j] = __builtin_amdgcn_mfma_f32_16x16x32_bf16(af[i], bf[j], acc[i][j], 0, 0, 0);
        __syncthreads();
    }

    const int crow0 = m0 + wr * 64 + lq * 4;
    const int ccol0 = p0 + wc * 64 + lr;
    #pragma unroll
    for (int i = 0; i < 4; i++) {
        float attv[4];
        if (MODE == 1) {
            #pragma unroll
            for (int v = 0; v < 4; v++) attv[v] = att[crow0 + i * 16 + v];
        }
        #pragma unroll
        for (int j = 0; j < 4; j++) {
            const int col = ccol0 + j * 16;
            const float bi = bias[col];
            #pragma unroll
            for (int v = 0; v < 4; v++) {
                const int row = crow0 + i * 16 + v;
                float val = fmaxf(acc[i][j][v] + bi, 0.0f);
                if (MODE == 0) ((unsigned short*)Cv)[(size_t)row * P_ + col] = f2bf(val);
                else           ((float*)Cv)[(size_t)row * P_ + col] = val * attv[v];
            }
        }
    }
}

// one wave per row: inv[r] = 1/(||X1[r,:]||+eps); wgt[r] = mask[n,b]*inv[r]
__global__ void rownorm_k(const unsigned short* __restrict__ X1,
                          const float* __restrict__ mask,
                          float* __restrict__ inv, float* __restrict__ wgt)
{
    const int r = blockIdx.x * 4 + (threadIdx.x >> 6);
    const int lane = threadIdx.x & 63;
    const unsigned short* row = X1 + (size_t)r * P_;
    bf16x8 u0 = *(const bf16x8*)(row + lane * 8);
    bf16x8 u1 = *(const bf16x8*)(row + 512 + lane * 8);
    float s = 0.f;
    #pragma unroll
    for (int k = 0; k < 8; k++) { float a = bf2f((unsigned short)u0[k]); s += a * a; }
    #pragma unroll
    for (int k = 0; k < 8; k++) { float a = bf2f((unsigned short)u1[k]); s += a * a; }
    #pragma unroll
    for (int off = 32; off > 0; off >>= 1) s += __shfl_down(s, off);
    if (lane == 0) {
        float iv = 1.f / (sqrtf(s) + 1e-8f);
        int b = r >> 11, n = r & (N_ - 1);
        inv[r] = iv;
        wgt[r] = mask[n * B_ + b] * iv;   // mask is [N,B] fp32
    }
}

__global__ void msum_k(const float* __restrict__ mask, float* __restrict__ msum)
{
    const int b = blockIdx.x;
    float s = 0.f;
    for (int n = threadIdx.x; n < N_; n += 256) s += mask[n * B_ + b];
    __shared__ float red[256];
    red[threadIdx.x] = s; __syncthreads();
    for (int o = 128; o > 0; o >>= 1) {
        if (threadIdx.x < o) red[threadIdx.x] += red[threadIdx.x + o];
        __syncthreads();
    }
    if (threadIdx.x == 0) msum[b] = red[0];
}

// wsvec[b,p] = sum_n wgt[b*N+n] * X1[b*N+n, p]
__global__ void colreduce_k(const unsigned short* __restrict__ X1,
                            const float* __restrict__ wgt,
                            float* __restrict__ wsvec)
{
    const int b  = blockIdx.y;
    const int nc = blockIdx.x;
    const int p4 = threadIdx.x * 4;
    float s0 = 0, s1 = 0, s2 = 0, s3 = 0;
    const int rbase = b * N_ + nc * 128;
    for (int n = 0; n < 128; n++) {
        const int r = rbase + n;
        const float w = wgt[r];
        unsigned long long d = *(const unsigned long long*)(X1 + (size_t)r * P_ + p4);
        s0 += w * bf2f((unsigned short)(d));
        s1 += w * bf2f((unsigned short)(d >> 16));
        s2 += w * bf2f((unsigned short)(d >> 32));
        s3 += w * bf2f((unsigned short)(d >> 48));
    }
    float* dst = wsvec + b * P_ + p4;
    atomicAdd(dst + 0, s0); atomicAdd(dst + 1, s1);
    atomicAdd(dst + 2, s2); atomicAdd(dst + 3, s3);
}

// att[r] = inv[r] * <X1[r,:], wsvec[b,:]> / msum[b]
__global__ void att_k(const unsigned short* __restrict__ X1,
                      const float* __restrict__ wsvec,
                      const float* __restrict__ inv,
                      const float* __restrict__ msum,
                      float* __restrict__ att)
{
    const int r = blockIdx.x * 4 + (threadIdx.x >> 6);
    const int lane = threadIdx.x & 63;
    const int b = r >> 11;
    const unsigned short* row = X1 + (size_t)r * P_;
    const float* w = wsvec + b * P_;
    bf16x8 u0 = *(const bf16x8*)(row + lane * 8);
    bf16x8 u1 = *(const bf16x8*)(row + 512 + lane * 8);
    float s = 0.f;
    #pragma unroll
    for (int k = 0; k < 8; k++) s += bf2f((unsigned short)u0[k]) * w[lane * 8 + k];
    #pragma unroll
    for (int k = 0; k < 8; k++) s += bf2f((unsigned short)u1[k]) * w[512 + lane * 8 + k];
    #pragma unroll
    for (int off = 32; off > 0; off >>= 1) s += __shfl_down(s, off);
    if (lane == 0) att[r] = s * inv[r] / msum[b];
}

extern "C" void kernel_launch(void* const* d_in, const int* in_sizes, int n_in,
                              void* d_out, int out_size, void* d_ws, size_t ws_size,
                              hipStream_t stream)
{
    // Inputs fp32 (per reference dtypes). Output fp32 [B,N,APP] = 128 MiB.
    const float* x    = (const float*)d_in[0];
    const float* mask = (const float*)d_in[1];
    const float* Wp   = (const float*)d_in[2];
    const float* bp   = (const float*)d_in[3];
    const float* Wv   = (const float*)d_in[4];
    const float* bv   = (const float*)d_in[5];
    float* out = (float*)d_out;

    // X1 (bf16, 64 MiB) parks in d_out's first half; dead before GEMM2 stores.
    unsigned short* X1 = (unsigned short*)d_out;

    const size_t xb_bytes = (size_t)M_ * D_ * 2;        // 64 MiB
    const size_t wb_bytes = (size_t)P_ * D_ * 2;        // 2 MiB
    const size_t f_bytes  = 3 * (size_t)M_ * 4 + (size_t)B_ * P_ * 4 + 64;
    const bool big_ws = ws_size >= xb_bytes + 2 * wb_bytes + f_bytes;

    char* ws = (char*)d_ws;
    size_t off = 0;
    unsigned short *xb = nullptr, *Wpb = nullptr, *Wvb = nullptr;
    if (big_ws) {
        xb  = (unsigned short*)(ws + off); off += xb_bytes;
        Wpb = (unsigned short*)(ws + off); off += wb_bytes;
        Wvb = (unsigned short*)(ws + off); off += wb_bytes;
    }
    float* inv  = (float*)(ws + off); off += (size_t)M_ * 4;
    float* wgt  = (float*)(ws + off); off += (size_t)M_ * 4;
    float* att  = (float*)(ws + off); off += (size_t)M_ * 4;
    float* wsv  = (float*)(ws + off); off += (size_t)B_ * P_ * 4;
    float* msum = (float*)(ws + off); off += 64;

    hipMemsetAsync(wsv, 0, (size_t)B_ * P_ * 4, stream);

    dim3 g(P_ / 128, M_ / 128);   // 8 x 256 tiles
    if (big_ws) {
        cvt_k<<<2048, 256, 0, stream>>>(x,  xb,  M_ * D_);
        cvt_k<<<256,  256, 0, stream>>>(Wp, Wpb, P_ * D_);
        cvt_k<<<256,  256, 0, stream>>>(Wv, Wvb, P_ * D_);
        gemm_bf<0><<<g, 256, 0, stream>>>(xb, Wpb, bp, nullptr, X1);
    } else {
        gemm_f32<0><<<g, 256, 0, stream>>>(x, Wp, bp, nullptr, X1);
    }
    rownorm_k<<<M_ / 4, 256, 0, stream>>>(X1, mask, inv, wgt);
    msum_k<<<B_, 256, 0, stream>>>(mask, msum);
    colreduce_k<<<dim3(16, B_), 256, 0, stream>>>(X1, wgt, wsv);
    att_k<<<M_ / 4, 256, 0, stream>>>(X1, wsv, inv, msum, att);
    if (big_ws) gemm_bf<1><<<g, 256, 0, stream>>>(xb, Wvb, bv, att, out);
    else        gemm_f32<1><<<g, 256, 0, stream>>>(x, Wv, bv, att, out);
}

// Round 5
// 434.324 us; speedup vs baseline: 1.0973x; 1.0973x over previous
//
#include <hip/hip_runtime.h>

#define B_  16
#define N_  2048
#define D_  1024
#define P_  1024
#define M_  (B_*N_)   // 32768

typedef __attribute__((ext_vector_type(8))) short bf16x8;
typedef __attribute__((ext_vector_type(4))) float f32x4;

__device__ __forceinline__ float bf2f(unsigned short u) {
    union { unsigned int i; float f; } v; v.i = ((unsigned int)u) << 16; return v.f;
}
__device__ __forceinline__ unsigned short f2bf(float f) {
    union { unsigned int i; float f; } v; v.f = f;
    unsigned int i = v.i;
    return (unsigned short)((i + 0x7FFFu + ((i >> 16) & 1u)) >> 16);   // RNE
}

__device__ __forceinline__ void async_cp16(const void* g, void* s) {
    __builtin_amdgcn_global_load_lds((const __attribute__((address_space(1))) void*)g,
                                     (__attribute__((address_space(3))) void*)s,
                                     16, 0, 0);
}

// one kernel converts all three fp32 inputs to bf16 (fewer dispatches)
__global__ void cvt_all_k(const float* __restrict__ x,  unsigned short* __restrict__ xb,
                          const float* __restrict__ Wp, unsigned short* __restrict__ Wpb,
                          const float* __restrict__ Wv, unsigned short* __restrict__ Wvb)
{
    const int stride = gridDim.x * 256 * 4;
    const int base = (blockIdx.x * 256 + threadIdx.x) * 4;
    for (int i = base; i < M_ * D_; i += stride) {
        float4 v = *(const float4*)(x + i);
        union { unsigned short u[4]; unsigned long long ll; } p;
        p.u[0]=f2bf(v.x); p.u[1]=f2bf(v.y); p.u[2]=f2bf(v.z); p.u[3]=f2bf(v.w);
        *(unsigned long long*)(xb + i) = p.ll;
    }
    for (int i = base; i < P_ * D_; i += stride) {
        float4 v = *(const float4*)(Wp + i);
        union { unsigned short u[4]; unsigned long long ll; } p;
        p.u[0]=f2bf(v.x); p.u[1]=f2bf(v.y); p.u[2]=f2bf(v.z); p.u[3]=f2bf(v.w);
        *(unsigned long long*)(Wpb + i) = p.ll;
    }
    for (int i = base; i < P_ * D_; i += stride) {
        float4 v = *(const float4*)(Wv + i);
        union { unsigned short u[4]; unsigned long long ll; } p;
        p.u[0]=f2bf(v.x); p.u[1]=f2bf(v.y); p.u[2]=f2bf(v.z); p.u[3]=f2bf(v.w);
        *(unsigned long long*)(Wvb + i) = p.ll;
    }
}

// ---------- bf16 GEMM, 128x128 tile, XOR-swizzled LDS, XCD-aware 1-D grid ----
// acc[m,p] = sum_k A[m,k]*W[p,k]
// MODE 0: X1_bf16 = f2bf(relu(acc+bias));  MODE 1: out_f32 = att[m]*relu(acc+bias)
// LDS swizzle: logical 16B chunk c of row r stored at physical c ^ ((r>>1)&3).
// Staging keeps dest = base + lane*16 (HW rule) and permutes the SOURCE chunk;
// fragment ds_read_b128 then spreads all 32 banks at 2-way (free, m136).
template<int MODE>
__global__ __launch_bounds__(256) void gemm_bf(const unsigned short* __restrict__ A,
                                               const unsigned short* __restrict__ W,
                                               const float* __restrict__ bias,
                                               const float* __restrict__ att,
                                               void* __restrict__ Cv)
{
    const int K = D_, BK = 32;
    __shared__ unsigned short As[128 * 32];
    __shared__ unsigned short Bs[128 * 32];

    // XCD-aware remap: any 64 consecutive ids cover an 8x8 (bx,by) tile, and
    // under id%8 XCD round-robin each y-slab's 8 column tiles stay on one XCD.
    const int id = blockIdx.x;
    const int bx = (id >> 3) & 7;
    const int by = ((id >> 6) << 3) | (id & 7);
    const int m0 = by * 128, p0 = bx * 128;

    const int wave = threadIdx.x >> 6, lane = threadIdx.x & 63;
    const int wr = wave >> 1, wc = wave & 1;

    // staging: 16 rows x 4 chunks per inst; source chunk XOR-permuted
    const int srow  = wave * 32 + (lane >> 2);
    const int schk  = (lane & 3) ^ ((lane >> 3) & 3);   // logical chunk for this slot
    const int scolg = schk * 8;                          // global col offset (elems)
    const int scold = (lane & 3) * 8;                    // LDS dest offset (physical)
    const unsigned short* ag = A + (size_t)(m0 + srow) * K + scolg;
    const unsigned short* bg = W + (size_t)(p0 + srow) * K + scolg;
    unsigned short* as = &As[srow * BK + scold];
    unsigned short* bs = &Bs[srow * BK + scold];

    f32x4 acc[4][4];
    #pragma unroll
    for (int i = 0; i < 4; i++)
        #pragma unroll
        for (int j = 0; j < 4; j++) acc[i][j] = (f32x4){0.f,0.f,0.f,0.f};

    // fragment gather: logical chunk lq of row lr lives at physical lq^((lr>>1)&3)
    const int lr = lane & 15, lq = lane >> 4;
    const int swz = (lr >> 1) & 3;
    const unsigned short* Ar = &As[(wr * 64 + lr) * BK + ((lq ^ swz) * 8)];
    const unsigned short* Br = &Bs[(wc * 64 + lr) * BK + ((lq ^ swz) * 8)];

    for (int kb = 0; kb < K; kb += BK) {
        async_cp16(ag + kb,          as);
        async_cp16(ag + 16 * K + kb, as + 16 * BK);
        async_cp16(bg + kb,          bs);
        async_cp16(bg + 16 * K + kb, bs + 16 * BK);
        __syncthreads();
        bf16x8 af[4], bf[4];
        #pragma unroll
        for (int i = 0; i < 4; i++) af[i] = *(const bf16x8*)(Ar + i * 16 * BK);
        #pragma unroll
        for (int j = 0; j < 4; j++) bf[j] = *(const bf16x8*)(Br + j * 16 * BK);
        #pragma unroll
        for (int i = 0; i < 4; i++)
            #pragma unroll
            for (int j = 0; j < 4; j++)
                acc[i][j] = __builtin_amdgcn_mfma_f32_16x16x32_bf16(af[i], bf[j], acc[i][j], 0, 0, 0);
        __syncthreads();
    }

    // C/D layout: col = lane&15, row = (lane>>4)*4 + reg   [m89-verified]
    const int crow0 = m0 + wr * 64 + lq * 4;
    const int ccol0 = p0 + wc * 64 + lr;
    #pragma unroll
    for (int i = 0; i < 4; i++) {
        float attv[4];
        if (MODE == 1) {
            #pragma unroll
            for (int v = 0; v < 4; v++) attv[v] = att[crow0 + i * 16 + v];
        }
        #pragma unroll
        for (int j = 0; j < 4; j++) {
            const int col = ccol0 + j * 16;
            const float bi = bias[col];
            #pragma unroll
            for (int v = 0; v < 4; v++) {
                const int row = crow0 + i * 16 + v;
                float val = fmaxf(acc[i][j][v] + bi, 0.0f);
                if (MODE == 0) ((unsigned short*)Cv)[(size_t)row * P_ + col] = f2bf(val);
                else           ((float*)Cv)[(size_t)row * P_ + col] = val * attv[v];
            }
        }
    }
}

// ---------- fallback fp32-staged GEMM (only if ws too small; unused per R4) --
template<int MODE>
__global__ __launch_bounds__(256) void gemm_f32(const float* __restrict__ A,
                                                const float* __restrict__ W,
                                                const float* __restrict__ bias,
                                                const float* __restrict__ att,
                                                void* __restrict__ Cv)
{
    const int K = D_, BK = 32;
    __shared__ float As[128 * 32];
    __shared__ float Bs[128 * 32];
    const int id = blockIdx.x;
    const int bx = (id >> 3) & 7;
    const int by = ((id >> 6) << 3) | (id & 7);
    const int m0 = by * 128, p0 = bx * 128;
    const int wave = threadIdx.x >> 6, lane = threadIdx.x & 63;
    const int wr = wave >> 1, wc = wave & 1;
    const int srow = wave * 32 + (lane >> 3);
    const int scol = (lane & 7) * 4;
    const float* ag = A + (size_t)(m0 + srow) * K + scol;
    const float* bg = W + (size_t)(p0 + srow) * K + scol;
    float* as = &As[srow * BK + scol];
    float* bs = &Bs[srow * BK + scol];
    f32x4 acc[4][4];
    #pragma unroll
    for (int i = 0; i < 4; i++)
        #pragma unroll
        for (int j = 0; j < 4; j++) acc[i][j] = (f32x4){0.f,0.f,0.f,0.f};
    const int lr = lane & 15, lq = lane >> 4;
    const float* Ar = &As[(wr * 64 + lr) * BK + lq * 8];
    const float* Br = &Bs[(wc * 64 + lr) * BK + lq * 8];
    for (int kb = 0; kb < K; kb += BK) {
        #pragma unroll
        for (int s = 0; s < 4; s++) {
            async_cp16(ag + (size_t)s * 8 * K + kb, as + s * 8 * BK);
            async_cp16(bg + (size_t)s * 8 * K + kb, bs + s * 8 * BK);
        }
        __syncthreads();
        bf16x8 af[4], bf[4];
        #pragma unroll
        for (int i = 0; i < 4; i++) {
            f32x4 a0 = *(const f32x4*)(Ar + i * 16 * BK);
            f32x4 a1 = *(const f32x4*)(Ar + i * 16 * BK + 4);
            #pragma unroll
            for (int e = 0; e < 4; e++) {
                union { float f; unsigned int u; } c;
                c.f = a0[e]; af[i][e]     = (short)(c.u >> 16);
                c.f = a1[e]; af[i][e + 4] = (short)(c.u >> 16);
            }
        }
        #pragma unroll
        for (int j = 0; j < 4; j++) {
            f32x4 b0 = *(const f32x4*)(Br + j * 16 * BK);
            f32x4 b1 = *(const f32x4*)(Br + j * 16 * BK + 4);
            #pragma unroll
            for (int e = 0; e < 4; e++) {
                union { float f; unsigned int u; } c;
                c.f = b0[e]; bf[j][e]     = (short)(c.u >> 16);
                c.f = b1[e]; bf[j][e + 4] = (short)(c.u >> 16);
            }
        }
        #pragma unroll
        for (int i = 0; i < 4; i++)
            #pragma unroll
            for (int j = 0; j < 4; j++)
                acc[i][j] = __builtin_amdgcn_mfma_f32_16x16x32_bf16(af[i], bf[j], acc[i][j], 0, 0, 0);
        __syncthreads();
    }
    const int crow0 = m0 + wr * 64 + lq * 4;
    const int ccol0 = p0 + wc * 64 + lr;
    #pragma unroll
    for (int i = 0; i < 4; i++) {
        float attv[4];
        if (MODE == 1) {
            #pragma unroll
            for (int v = 0; v < 4; v++) attv[v] = att[crow0 + i * 16 + v];
        }
        #pragma unroll
        for (int j = 0; j < 4; j++) {
            const int col = ccol0 + j * 16;
            const float bi = bias[col];
            #pragma unroll
            for (int v = 0; v < 4; v++) {
                const int row = crow0 + i * 16 + v;
                float val = fmaxf(acc[i][j][v] + bi, 0.0f);
                if (MODE == 0) ((unsigned short*)Cv)[(size_t)row * P_ + col] = f2bf(val);
                else           ((float*)Cv)[(size_t)row * P_ + col] = val * attv[v];
            }
        }
    }
}

// ---------- fused rownorm + weighted column-reduce + mask-sum ----------------
// One X1 read instead of two. grid (16 nchunks, 16 b), 4 waves/block.
// Wave handles 32 rows; per-lane VGPR accumulators (16 cols/lane); transposed
// LDS layout for the cross-wave reduce (bank = lane%32, 2-way = free).
__global__ __launch_bounds__(256) void fused_nc_k(const unsigned short* __restrict__ X1,
                                                  const float* __restrict__ mask,
                                                  float* __restrict__ inv,
                                                  float* __restrict__ wsv,
                                                  float* __restrict__ msum)
{
    __shared__ float accw[4][1024];
    __shared__ float mred[4];
    const int b = blockIdx.y, nc = blockIdx.x;
    const int wave = threadIdx.x >> 6, lane = threadIdx.x & 63;
    float acc[16];
    #pragma unroll
    for (int e = 0; e < 16; e++) acc[e] = 0.f;
    float msub = 0.f;
    const int rbase = b * N_ + nc * 128 + wave * 32;
    const int nbase = nc * 128 + wave * 32;
    for (int t = 0; t < 32; t++) {
        const int r = rbase + t;
        const unsigned short* row = X1 + (size_t)r * P_;
        bf16x8 u0 = *(const bf16x8*)(row + lane * 16);
        bf16x8 u1 = *(const bf16x8*)(row + lane * 16 + 8);
        float v[16], s = 0.f;
        #pragma unroll
        for (int e = 0; e < 8; e++) { v[e] = bf2f((unsigned short)u0[e]); s += v[e]*v[e]; }
        #pragma unroll
        for (int e = 0; e < 8; e++) { v[8+e] = bf2f((unsigned short)u1[e]); s += v[8+e]*v[8+e]; }
        #pragma unroll
        for (int off = 32; off > 0; off >>= 1) s += __shfl_down(s, off);
        s = __shfl(s, 0);
        const float iv = 1.f / (sqrtf(s) + 1e-8f);
        const float mk = mask[(nbase + t) * B_ + b];
        if (lane == 0) { inv[r] = iv; msub += mk; }
        const float w = mk * iv;
        #pragma unroll
        for (int e = 0; e < 16; e++) acc[e] += w * v[e];
    }
    #pragma unroll
    for (int e = 0; e < 16; e++) accw[wave][e * 64 + lane] = acc[e];   // transposed
    if (lane == 0) mred[wave] = msub;
    __syncthreads();
    #pragma unroll
    for (int q = 0; q < 4; q++) {
        const int p = threadIdx.x * 4 + q;          // physical idx
        const int col = (p & 63) * 16 + (p >> 6);   // logical column
        float ssum = accw[0][p] + accw[1][p] + accw[2][p] + accw[3][p];
        atomicAdd(&wsv[b * P_ + col], ssum);
    }
    if (threadIdx.x == 0) atomicAdd(&msum[b], mred[0] + mred[1] + mred[2] + mred[3]);
}

// att[r] = inv[r] * <X1[r,:], wsv[b,:]> / msum[b]; one wave per row
__global__ void att_k(const unsigned short* __restrict__ X1,
                      const float* __restrict__ wsvec,
                      const float* __restrict__ inv,
                      const float* __restrict__ msum,
                      float* __restrict__ att)
{
    const int r = blockIdx.x * 4 + (threadIdx.x >> 6);
    const int lane = threadIdx.x & 63;
    const int b = r >> 11;
    const unsigned short* row = X1 + (size_t)r * P_;
    const float* w = wsvec + b * P_;
    bf16x8 u0 = *(const bf16x8*)(row + lane * 8);
    bf16x8 u1 = *(const bf16x8*)(row + 512 + lane * 8);
    float s = 0.f;
    #pragma unroll
    for (int k = 0; k < 8; k++) s += bf2f((unsigned short)u0[k]) * w[lane * 8 + k];
    #pragma unroll
    for (int k = 0; k < 8; k++) s += bf2f((unsigned short)u1[k]) * w[512 + lane * 8 + k];
    #pragma unroll
    for (int off = 32; off > 0; off >>= 1) s += __shfl_down(s, off);
    if (lane == 0) att[r] = s * inv[r] / msum[b];
}

extern "C" void kernel_launch(void* const* d_in, const int* in_sizes, int n_in,
                              void* d_out, int out_size, void* d_ws, size_t ws_size,
                              hipStream_t stream)
{
    const float* x    = (const float*)d_in[0];
    const float* mask = (const float*)d_in[1];
    const float* Wp   = (const float*)d_in[2];
    const float* bp   = (const float*)d_in[3];
    const float* Wv   = (const float*)d_in[4];
    const float* bv   = (const float*)d_in[5];
    float* out = (float*)d_out;

    // X1 (bf16, 64 MiB) parks in d_out's first half; dead before GEMM2 stores.
    unsigned short* X1 = (unsigned short*)d_out;

    const size_t xb_bytes = (size_t)M_ * D_ * 2;
    const size_t wb_bytes = (size_t)P_ * D_ * 2;
    const size_t f_bytes  = 2 * (size_t)M_ * 4 + (size_t)B_ * P_ * 4 + 64;
    const bool big_ws = ws_size >= xb_bytes + 2 * wb_bytes + f_bytes;

    char* ws = (char*)d_ws;
    size_t off = 0;
    unsigned short *xb = nullptr, *Wpb = nullptr, *Wvb = nullptr;
    if (big_ws) {
        xb  = (unsigned short*)(ws + off); off += xb_bytes;
        Wpb = (unsigned short*)(ws + off); off += wb_bytes;
        Wvb = (unsigned short*)(ws + off); off += wb_bytes;
    }
    float* inv  = (float*)(ws + off); off += (size_t)M_ * 4;
    float* att  = (float*)(ws + off); off += (size_t)M_ * 4;
    float* wsv  = (float*)(ws + off); off += (size_t)B_ * P_ * 4;   // contiguous
    float* msum = (float*)(ws + off); off += 64;                    //  with wsv

    // zero wsv + msum in one memset (they're adjacent)
    hipMemsetAsync(wsv, 0, (size_t)B_ * P_ * 4 + 64, stream);

    const int gblocks = (P_ / 128) * (M_ / 128);   // 2048, 1-D XCD-remapped
    if (big_ws) {
        cvt_all_k<<<2048, 256, 0, stream>>>(x, xb, Wp, Wpb, Wv, Wvb);
        gemm_bf<0><<<gblocks, 256, 0, stream>>>(xb, Wpb, bp, nullptr, X1);
    } else {
        gemm_f32<0><<<gblocks, 256, 0, stream>>>(x, Wp, bp, nullptr, X1);
    }
    fused_nc_k<<<dim3(16, B_), 256, 0, stream>>>(X1, mask, inv, wsv, msum);
    att_k<<<M_ / 4, 256, 0, stream>>>(X1, wsv, inv, msum, att);
    if (big_ws) gemm_bf<1><<<gblocks, 256, 0, stream>>>(xb, Wvb, bv, att, out);
    else        gemm_f32<1><<<gblocks, 256, 0, stream>>>(x, Wv, bv, att, out);
}

// Round 6
// 424.948 us; speedup vs baseline: 1.1215x; 1.0221x over previous
//
#include <hip/hip_runtime.h>

#define B_  16
#define N_  2048
#define D_  1024
#define P_  1024
#define M_  (B_*N_)   // 32768

typedef __attribute__((ext_vector_type(8))) short bf16x8;
typedef __attribute__((ext_vector_type(4))) float f32x4;

__device__ __forceinline__ float bf2f(unsigned short u) {
    union { unsigned int i; float f; } v; v.i = ((unsigned int)u) << 16; return v.f;
}
__device__ __forceinline__ unsigned short f2bf(float f) {
    union { unsigned int i; float f; } v; v.f = f;
    unsigned int i = v.i;
    return (unsigned short)((i + 0x7FFFu + ((i >> 16) & 1u)) >> 16);   // RNE
}

__device__ __forceinline__ void async_cp16(const void* g, void* s) {
    __builtin_amdgcn_global_load_lds((const __attribute__((address_space(1))) void*)g,
                                     (__attribute__((address_space(3))) void*)s,
                                     16, 0, 0);
}

// one kernel converts all three fp32 inputs to bf16
__global__ void cvt_all_k(const float* __restrict__ x,  unsigned short* __restrict__ xb,
                          const float* __restrict__ Wp, unsigned short* __restrict__ Wpb,
                          const float* __restrict__ Wv, unsigned short* __restrict__ Wvb)
{
    const int stride = gridDim.x * 256 * 4;
    const int base = (blockIdx.x * 256 + threadIdx.x) * 4;
    for (int i = base; i < M_ * D_; i += stride) {
        float4 v = *(const float4*)(x + i);
        union { unsigned short u[4]; unsigned long long ll; } p;
        p.u[0]=f2bf(v.x); p.u[1]=f2bf(v.y); p.u[2]=f2bf(v.z); p.u[3]=f2bf(v.w);
        *(unsigned long long*)(xb + i) = p.ll;
    }
    for (int i = base; i < P_ * D_; i += stride) {
        float4 v = *(const float4*)(Wp + i);
        union { unsigned short u[4]; unsigned long long ll; } p;
        p.u[0]=f2bf(v.x); p.u[1]=f2bf(v.y); p.u[2]=f2bf(v.z); p.u[3]=f2bf(v.w);
        *(unsigned long long*)(Wpb + i) = p.ll;
    }
    for (int i = base; i < P_ * D_; i += stride) {
        float4 v = *(const float4*)(Wv + i);
        union { unsigned short u[4]; unsigned long long ll; } p;
        p.u[0]=f2bf(v.x); p.u[1]=f2bf(v.y); p.u[2]=f2bf(v.z); p.u[3]=f2bf(v.w);
        *(unsigned long long*)(Wvb + i) = p.ll;
    }
}

// ---------- bf16 GEMM, 128x128 tile, BK=64 (16 barriers), swizzled LDS -------
// acc[m,p] = sum_k A[m,k]*W[p,k]
// MODE 0: X1_bf16 = f2bf(relu(acc+bias));  MODE 1: out_f32 = att[m]*relu(acc+bias)
// LDS swizzle: 16B chunk c (0..7) of row r stored at physical c ^ (r&7).
// Staging: dest = wave-uniform base + lane*16 (HW rule); SOURCE col permuted.
// Fragment ds_read_b128: phys chunk uniform over 0..7 across the wave -> all
// 32 banks at the b128 minimum aliasing (counter measured 0 at BK=32).
template<int MODE>
__global__ __launch_bounds__(256) void gemm_bf(const unsigned short* __restrict__ A,
                                               const unsigned short* __restrict__ W,
                                               const float* __restrict__ bias,
                                               const float* __restrict__ att,
                                               void* __restrict__ Cv)
{
    const int K = D_, BK = 64;
    __shared__ unsigned short As[128 * 64];   // 16 KiB
    __shared__ unsigned short Bs[128 * 64];   // 16 KiB

    // XCD-aware remap: 64 consecutive ids = 8x8 (bx,by) tile; id%8 = XCD.
    const int id = blockIdx.x;
    const int bx = (id >> 3) & 7;
    const int by = ((id >> 6) << 3) | (id & 7);
    const int m0 = by * 128, p0 = bx * 128;

    const int wave = threadIdx.x >> 6, lane = threadIdx.x & 63;
    const int wr = wave >> 1, wc = wave & 1;

    // staging: 1 inst = 8 rows x 128B. row_local = lane>>3, phys slot = lane&7,
    // logical chunk = slot ^ (row&7) = (lane&7) ^ (lane>>3)   (row&7 == lane>>3)
    const int srow = wave * 32 + (lane >> 3);
    const int scol = (((lane & 7) ^ (lane >> 3)) & 7) * 8;   // global col (shorts)
    const unsigned short* ag = A + (size_t)(m0 + srow) * K + scol;
    const unsigned short* bg = W + (size_t)(p0 + srow) * K + scol;
    unsigned short* as = &As[srow * BK + (lane & 7) * 8];    // == base + lane*16B
    unsigned short* bs = &Bs[srow * BK + (lane & 7) * 8];

    f32x4 acc[4][4];
    #pragma unroll
    for (int i = 0; i < 4; i++)
        #pragma unroll
        for (int j = 0; j < 4; j++) acc[i][j] = (f32x4){0.f,0.f,0.f,0.f};

    // fragment gather (16x16x32): m = lane&15, k-chunk = h*4 + (lane>>4)
    const int lr = lane & 15, lq = lane >> 4;
    const unsigned short* ArR = &As[(wr * 64 + lr) * BK];
    const unsigned short* BrR = &Bs[(wc * 64 + lr) * BK];
    const int c0 = ((lq       ^ (lr & 7)) & 7) * 8;   // k-half 0
    const int c1 = (((lq | 4) ^ (lr & 7)) & 7) * 8;   // k-half 1

    for (int kb = 0; kb < K; kb += BK) {
        #pragma unroll
        for (int s = 0; s < 4; s++) {
            async_cp16(ag + (size_t)s * 8 * K + kb, as + s * 8 * BK);
            async_cp16(bg + (size_t)s * 8 * K + kb, bs + s * 8 * BK);
        }
        __syncthreads();   // drain staging
        bf16x8 af[2][4], bfr[2][4];
        #pragma unroll
        for (int i = 0; i < 4; i++) {
            af[0][i] = *(const bf16x8*)(ArR + i * 16 * BK + c0);
            af[1][i] = *(const bf16x8*)(ArR + i * 16 * BK + c1);
        }
        #pragma unroll
        for (int j = 0; j < 4; j++) {
            bfr[0][j] = *(const bf16x8*)(BrR + j * 16 * BK + c0);
            bfr[1][j] = *(const bf16x8*)(BrR + j * 16 * BK + c1);
        }
        #pragma unroll
        for (int h = 0; h < 2; h++)
            #pragma unroll
            for (int i = 0; i < 4; i++)
                #pragma unroll
                for (int j = 0; j < 4; j++)
                    acc[i][j] = __builtin_amdgcn_mfma_f32_16x16x32_bf16(af[h][i], bfr[h][j], acc[i][j], 0, 0, 0);
        __syncthreads();   // reads done before next stage overwrites
    }

    // C/D layout: col = lane&15, row = (lane>>4)*4 + reg   [m89-verified]
    const int crow0 = m0 + wr * 64 + lq * 4;
    const int ccol0 = p0 + wc * 64 + lr;
    #pragma unroll
    for (int i = 0; i < 4; i++) {
        float attv[4];
        if (MODE == 1) {
            #pragma unroll
            for (int v = 0; v < 4; v++) attv[v] = att[crow0 + i * 16 + v];
        }
        #pragma unroll
        for (int j = 0; j < 4; j++) {
            const int col = ccol0 + j * 16;
            const float bi = bias[col];
            #pragma unroll
            for (int v = 0; v < 4; v++) {
                const int row = crow0 + i * 16 + v;
                float val = fmaxf(acc[i][j][v] + bi, 0.0f);
                if (MODE == 0) ((unsigned short*)Cv)[(size_t)row * P_ + col] = f2bf(val);
                else           ((float*)Cv)[(size_t)row * P_ + col] = val * attv[v];
            }
        }
    }
}

// ---------- fallback fp32-staged GEMM (only if ws too small) -----------------
template<int MODE>
__global__ __launch_bounds__(256) void gemm_f32(const float* __restrict__ A,
                                                const float* __restrict__ W,
                                                const float* __restrict__ bias,
                                                const float* __restrict__ att,
                                                void* __restrict__ Cv)
{
    const int K = D_, BK = 32;
    __shared__ float As[128 * 32];
    __shared__ float Bs[128 * 32];
    const int id = blockIdx.x;
    const int bx = (id >> 3) & 7;
    const int by = ((id >> 6) << 3) | (id & 7);
    const int m0 = by * 128, p0 = bx * 128;
    const int wave = threadIdx.x >> 6, lane = threadIdx.x & 63;
    const int wr = wave >> 1, wc = wave & 1;
    const int srow = wave * 32 + (lane >> 3);
    const int scol = (lane & 7) * 4;
    const float* ag = A + (size_t)(m0 + srow) * K + scol;
    const float* bg = W + (size_t)(p0 + srow) * K + scol;
    float* as = &As[srow * BK + scol];
    float* bs = &Bs[srow * BK + scol];
    f32x4 acc[4][4];
    #pragma unroll
    for (int i = 0; i < 4; i++)
        #pragma unroll
        for (int j = 0; j < 4; j++) acc[i][j] = (f32x4){0.f,0.f,0.f,0.f};
    const int lr = lane & 15, lq = lane >> 4;
    const float* Ar = &As[(wr * 64 + lr) * BK + lq * 8];
    const float* Br = &Bs[(wc * 64 + lr) * BK + lq * 8];
    for (int kb = 0; kb < K; kb += BK) {
        #pragma unroll
        for (int s = 0; s < 4; s++) {
            async_cp16(ag + (size_t)s * 8 * K + kb, as + s * 8 * BK);
            async_cp16(bg + (size_t)s * 8 * K + kb, bs + s * 8 * BK);
        }
        __syncthreads();
        bf16x8 af[4], bf[4];
        #pragma unroll
        for (int i = 0; i < 4; i++) {
            f32x4 a0 = *(const f32x4*)(Ar + i * 16 * BK);
            f32x4 a1 = *(const f32x4*)(Ar + i * 16 * BK + 4);
            #pragma unroll
            for (int e = 0; e < 4; e++) {
                union { float f; unsigned int u; } c;
                c.f = a0[e]; af[i][e]     = (short)(c.u >> 16);
                c.f = a1[e]; af[i][e + 4] = (short)(c.u >> 16);
            }
        }
        #pragma unroll
        for (int j = 0; j < 4; j++) {
            f32x4 b0 = *(const f32x4*)(Br + j * 16 * BK);
            f32x4 b1 = *(const f32x4*)(Br + j * 16 * BK + 4);
            #pragma unroll
            for (int e = 0; e < 4; e++) {
                union { float f; unsigned int u; } c;
                c.f = b0[e]; bf[j][e]     = (short)(c.u >> 16);
                c.f = b1[e]; bf[j][e + 4] = (short)(c.u >> 16);
            }
        }
        #pragma unroll
        for (int i = 0; i < 4; i++)
            #pragma unroll
            for (int j = 0; j < 4; j++)
                acc[i][j] = __builtin_amdgcn_mfma_f32_16x16x32_bf16(af[i], bf[j], acc[i][j], 0, 0, 0);
        __syncthreads();
    }
    const int crow0 = m0 + wr * 64 + lq * 4;
    const int ccol0 = p0 + wc * 64 + lr;
    #pragma unroll
    for (int i = 0; i < 4; i++) {
        float attv[4];
        if (MODE == 1) {
            #pragma unroll
            for (int v = 0; v < 4; v++) attv[v] = att[crow0 + i * 16 + v];
        }
        #pragma unroll
        for (int j = 0; j < 4; j++) {
            const int col = ccol0 + j * 16;
            const float bi = bias[col];
            #pragma unroll
            for (int v = 0; v < 4; v++) {
                const int row = crow0 + i * 16 + v;
                float val = fmaxf(acc[i][j][v] + bi, 0.0f);
                if (MODE == 0) ((unsigned short*)Cv)[(size_t)row * P_ + col] = f2bf(val);
                else           ((float*)Cv)[(size_t)row * P_ + col] = val * attv[v];
            }
        }
    }
}

// ---------- fused rownorm + weighted column-reduce + mask-sum ----------------
// grid (32 nchunks, 16 b) = 512 blocks (2/CU); wave handles 16 rows.
__global__ __launch_bounds__(256) void fused_nc_k(const unsigned short* __restrict__ X1,
                                                  const float* __restrict__ mask,
                                                  float* __restrict__ inv,
                                                  float* __restrict__ wsv,
                                                  float* __restrict__ msum)
{
    __shared__ float accw[4][1024];
    __shared__ float mred[4];
    const int b = blockIdx.y, nc = blockIdx.x;
    const int wave = threadIdx.x >> 6, lane = threadIdx.x & 63;
    float acc[16];
    #pragma unroll
    for (int e = 0; e < 16; e++) acc[e] = 0.f;
    float msub = 0.f;
    const int rbase = b * N_ + nc * 64 + wave * 16;
    const int nbase = nc * 64 + wave * 16;
    for (int t = 0; t < 16; t++) {
        const int r = rbase + t;
        const unsigned short* row = X1 + (size_t)r * P_;
        bf16x8 u0 = *(const bf16x8*)(row + lane * 16);
        bf16x8 u1 = *(const bf16x8*)(row + lane * 16 + 8);
        float v[16], s = 0.f;
        #pragma unroll
        for (int e = 0; e < 8; e++) { v[e] = bf2f((unsigned short)u0[e]); s += v[e]*v[e]; }
        #pragma unroll
        for (int e = 0; e < 8; e++) { v[8+e] = bf2f((unsigned short)u1[e]); s += v[8+e]*v[8+e]; }
        #pragma unroll
        for (int off = 32; off > 0; off >>= 1) s += __shfl_down(s, off);
        s = __shfl(s, 0);
        const float iv = 1.f / (sqrtf(s) + 1e-8f);
        const float mk = mask[(nbase + t) * B_ + b];
        if (lane == 0) { inv[r] = iv; msub += mk; }
        const float w = mk * iv;
        #pragma unroll
        for (int e = 0; e < 16; e++) acc[e] += w * v[e];
    }
    #pragma unroll
    for (int e = 0; e < 16; e++) accw[wave][e * 64 + lane] = acc[e];   // transposed
    if (lane == 0) mred[wave] = msub;
    __syncthreads();
    #pragma unroll
    for (int q = 0; q < 4; q++) {
        const int p = threadIdx.x * 4 + q;
        const int col = (p & 63) * 16 + (p >> 6);
        float ssum = accw[0][p] + accw[1][p] + accw[2][p] + accw[3][p];
        atomicAdd(&wsv[b * P_ + col], ssum);
    }
    if (threadIdx.x == 0) atomicAdd(&msum[b], mred[0] + mred[1] + mred[2] + mred[3]);
}

// att[r] = inv[r] * <X1[r,:], wsv[b,:]> / msum[b]; one wave per row
__global__ void att_k(const unsigned short* __restrict__ X1,
                      const float* __restrict__ wsvec,
                      const float* __restrict__ inv,
                      const float* __restrict__ msum,
                      float* __restrict__ att)
{
    const int r = blockIdx.x * 4 + (threadIdx.x >> 6);
    const int lane = threadIdx.x & 63;
    const int b = r >> 11;
    const unsigned short* row = X1 + (size_t)r * P_;
    const float* w = wsvec + b * P_;
    bf16x8 u0 = *(const bf16x8*)(row + lane * 8);
    bf16x8 u1 = *(const bf16x8*)(row + 512 + lane * 8);
    float s = 0.f;
    #pragma unroll
    for (int k = 0; k < 8; k++) s += bf2f((unsigned short)u0[k]) * w[lane * 8 + k];
    #pragma unroll
    for (int k = 0; k < 8; k++) s += bf2f((unsigned short)u1[k]) * w[512 + lane * 8 + k];
    #pragma unroll
    for (int off = 32; off > 0; off >>= 1) s += __shfl_down(s, off);
    if (lane == 0) att[r] = s * inv[r] / msum[b];
}

extern "C" void kernel_launch(void* const* d_in, const int* in_sizes, int n_in,
                              void* d_out, int out_size, void* d_ws, size_t ws_size,
                              hipStream_t stream)
{
    const float* x    = (const float*)d_in[0];
    const float* mask = (const float*)d_in[1];
    const float* Wp   = (const float*)d_in[2];
    const float* bp   = (const float*)d_in[3];
    const float* Wv   = (const float*)d_in[4];
    const float* bv   = (const float*)d_in[5];
    float* out = (float*)d_out;

    // X1 (bf16, 64 MiB) parks in d_out's first half; dead before GEMM2 stores.
    unsigned short* X1 = (unsigned short*)d_out;

    const size_t xb_bytes = (size_t)M_ * D_ * 2;
    const size_t wb_bytes = (size_t)P_ * D_ * 2;
    const size_t f_bytes  = 2 * (size_t)M_ * 4 + (size_t)B_ * P_ * 4 + 64;
    const bool big_ws = ws_size >= xb_bytes + 2 * wb_bytes + f_bytes;

    char* ws = (char*)d_ws;
    size_t off = 0;
    unsigned short *xb = nullptr, *Wpb = nullptr, *Wvb = nullptr;
    if (big_ws) {
        xb  = (unsigned short*)(ws + off); off += xb_bytes;
        Wpb = (unsigned short*)(ws + off); off += wb_bytes;
        Wvb = (unsigned short*)(ws + off); off += wb_bytes;
    }
    float* inv  = (float*)(ws + off); off += (size_t)M_ * 4;
    float* att  = (float*)(ws + off); off += (size_t)M_ * 4;
    float* wsv  = (float*)(ws + off); off += (size_t)B_ * P_ * 4;
    float* msum = (float*)(ws + off); off += 64;

    hipMemsetAsync(wsv, 0, (size_t)B_ * P_ * 4 + 64, stream);

    const int gblocks = (P_ / 128) * (M_ / 128);   // 2048, 1-D XCD-remapped
    if (big_ws) {
        cvt_all_k<<<2048, 256, 0, stream>>>(x, xb, Wp, Wpb, Wv, Wvb);
        gemm_bf<0><<<gblocks, 256, 0, stream>>>(xb, Wpb, bp, nullptr, X1);
    } else {
        gemm_f32<0><<<gblocks, 256, 0, stream>>>(x, Wp, bp, nullptr, X1);
    }
    fused_nc_k<<<dim3(32, B_), 256, 0, stream>>>(X1, mask, inv, wsv, msum);
    att_k<<<M_ / 4, 256, 0, stream>>>(X1, wsv, inv, msum, att);
    if (big_ws) gemm_bf<1><<<gblocks, 256, 0, stream>>>(xb, Wvb, bv, att, out);
    else        gemm_f32<1><<<gblocks, 256, 0, stream>>>(x, Wv, bv, att, out);
}